// Round 14
// baseline (742.761 us; speedup 1.0000x reference)
//
#include <hip/hip_runtime.h>
#include <math.h>

#define NN 50000
#define MPAD 50048   // 391 * 128
#define NE 800000
#define NG 64
#define FIN 128
#define FH 256      // heads * HID = 4*64, both layers
#define HID 64
#define NH 4
#define NOUT 10
#define NEG_SLOPE 0.2f
#define NSB ((NN + 1023) / 1024)   // 49 scan blocks

typedef unsigned short u16;
typedef __attribute__((ext_vector_type(8))) short short8;
typedef __attribute__((ext_vector_type(4))) float f32x4;

static __device__ __forceinline__ float leaky(float x){ return x > 0.f ? x : NEG_SLOPE * x; }
static __device__ __forceinline__ float elu1(float x){ return x > 0.f ? x : (__expf(x) - 1.f); }
static __device__ __forceinline__ float b2f(u16 u){
  union { unsigned int i; float f; } v; v.i = ((unsigned)u) << 16; return v.f;
}
static __device__ __forceinline__ u16 f2b(float f){
  union { float f; unsigned int i; } v; v.f = f;
  unsigned r = v.i + 0x7FFFu + ((v.i >> 16) & 1u);
  return (u16)(r >> 16);
}

static __device__ __forceinline__ void gl_lds16(const u16* g, u16* l){
  __builtin_amdgcn_global_load_lds(
      (const __attribute__((address_space(1))) void*)g,
      (__attribute__((address_space(3))) void*)l, 16, 0, 0);
}

// ---------------- fused: hist (+rank), x->bf16, W transposes (pure bf16), pooled zero
#define HIST_BLKS ((NE + 255) / 256)           // 3125
#define F2B_BLKS (NN * FIN / 4 / 256)          // 6250
#define W1_BLKS  (FIN * FH / 256)              // 128
#define W2_BLKS  (FH * FH / 256)               // 256
__global__ void k_histprep(const int* __restrict__ dst, int* __restrict__ cnt,
                           int* __restrict__ rank,
                           const float* __restrict__ x, u16* __restrict__ xh,
                           const float* __restrict__ W1, u16* __restrict__ Wt1,
                           const float* __restrict__ W2, u16* __restrict__ Wt2,
                           float* __restrict__ pooled)
{
  int b = blockIdx.x;
  if (b < HIST_BLKS){
    int i = b * 256 + threadIdx.x;
    if (i < NE) rank[i] = atomicAdd(&cnt[dst[i]], 1);
  } else if (b < HIST_BLKS + F2B_BLKS){
    int i = ((b - HIST_BLKS) * 256 + threadIdx.x) * 4;
    float4 v = *reinterpret_cast<const float4*>(x + i);
    ushort4 o; o.x = f2b(v.x); o.y = f2b(v.y); o.z = f2b(v.z); o.w = f2b(v.w);
    *reinterpret_cast<ushort4*>(xh + i) = o;
  } else if (b < HIST_BLKS + F2B_BLKS + W1_BLKS){
    int e = (b - HIST_BLKS - F2B_BLKS) * 256 + threadIdx.x;
    int k = e >> 8, c = e & 255;
    Wt1[(size_t)c * FIN + k] = f2b(W1[e]);
  } else if (b < HIST_BLKS + F2B_BLKS + W1_BLKS + W2_BLKS){
    int e = (b - HIST_BLKS - F2B_BLKS - W1_BLKS) * 256 + threadIdx.x;
    int k = e >> 8, c = e & 255;
    Wt2[(size_t)c * FH + k] = f2b(W2[e]);
  } else {
    float4 z = make_float4(0.f, 0.f, 0.f, 0.f);
    #pragma unroll
    for (int l = 0; l < 4; l++)
      *reinterpret_cast<float4*>(pooled + (l * 256 + threadIdx.x) * 4) = z;
  }
}

// scan stage 1: per-1024-chunk LOCAL exclusive prefix + block total
__global__ __launch_bounds__(256) void k_scan1(const int* __restrict__ cnt,
    int* __restrict__ offs, int* __restrict__ bsum)
{
  __shared__ int wsum[4];
  int t = threadIdx.x;
  int lane = t & 63, wv = t >> 6;
  int base = blockIdx.x * 1024 + t * 4;
  int4 v = make_int4(0, 0, 0, 0);
  if (base + 3 < NN) v = *reinterpret_cast<const int4*>(cnt + base);
  else {
    if (base + 0 < NN) v.x = cnt[base + 0];
    if (base + 1 < NN) v.y = cnt[base + 1];
    if (base + 2 < NN) v.z = cnt[base + 2];
  }
  int s = v.x + v.y + v.z + v.w;
  int incl = s;
  #pragma unroll
  for (int d = 1; d < 64; d <<= 1){
    int u = __shfl_up(incl, d);
    if (lane >= d) incl += u;
  }
  if (lane == 63) wsum[wv] = incl;
  __syncthreads();
  int woff = 0;
  #pragma unroll
  for (int i = 0; i < 4; i++) if (i < wv) woff += wsum[i];
  int texcl = woff + incl - s;
  int e0 = texcl, e1 = e0 + v.x, e2 = e1 + v.y, e3 = e2 + v.z;
  if (base + 3 < NN) *reinterpret_cast<int4*>(offs + base) = make_int4(e0, e1, e2, e3);
  else {
    if (base + 0 < NN) offs[base + 0] = e0;
    if (base + 1 < NN) offs[base + 1] = e1;
    if (base + 2 < NN) offs[base + 2] = e2;
  }
  if (t == 255) bsum[blockIdx.x] = woff + incl;
}

// per-block inline scan of the 49 block totals -> LDS (wave 0 computes)
static __device__ __forceinline__ void block_bpre(const int* __restrict__ bsum,
                                                  int* sb)
{
  int t = threadIdx.x;
  if (t < 64){
    int s = (t < NSB) ? bsum[t] : 0;
    int incl = s;
    #pragma unroll
    for (int d = 1; d < 64; d <<= 1){
      int u = __shfl_up(incl, d);
      if (t >= d) incl += u;
    }
    sb[t] = incl - s;
  }
  __syncthreads();
}

// atomic-free scatter; global offset = local offs + block prefix
__global__ __launch_bounds__(256) void k_scatter(const int* __restrict__ src,
    const int* __restrict__ dst, const int* __restrict__ offs,
    const int* __restrict__ bsum, const int* __restrict__ rank,
    int* __restrict__ csrc){
  __shared__ int sb[64];
  block_bpre(bsum, sb);
  int i = blockIdx.x * blockDim.x + threadIdx.x;
  if (i < NE){
    int d = dst[i];
    csrc[offs[d] + sb[d >> 10] + rank[i]] = src[i];
  }
}

// ---------------- bf16 MFMA GEMM (128x256 tile, 8 waves) + fused attention scores ----
// C[MPAD][256] = A[MPAD][K] @ Wt^T, Wt[256][K] bf16
template<int K>
__global__ __launch_bounds__(512) void k_gemm_bf(
    const u16* __restrict__ A, const u16* __restrict__ Wt, u16* __restrict__ C,
    const float* __restrict__ attn_l, const float* __restrict__ attn_r,
    float* __restrict__ el, float* __restrict__ er)
{
  __shared__ union {
    struct { u16 a[128 * 32]; u16 b[256 * 32]; } s;  // 8KB + 16KB
    u16 ct[128 * 256];                               // 64KB epilogue staging
  } L;
  int t = threadIdx.x;
  int wv = t >> 6, lane = t & 63;
  int row0 = blockIdx.x * 128;
  int lr = lane & 15, lk = lane >> 4;
  int wm = wv >> 2, wn = wv & 3;       // wave grid 2 x 4

  f32x4 acc[4][4];
  #pragma unroll
  for (int m = 0; m < 4; m++)
    #pragma unroll
    for (int n = 0; n < 4; n++) acc[m][n] = (f32x4){0.f, 0.f, 0.f, 0.f};

  const u16* asrc = A + (size_t)(row0 + wv * 16 + (lane >> 2)) * K + (lane & 3) * 8;
  u16* aldst = &L.s.a[wv * 512];
  const u16* bsrc0 = Wt + (size_t)(wv * 32 + (lane >> 2)) * K + (lane & 3) * 8;
  const u16* bsrc1 = Wt + (size_t)(wv * 32 + 16 + (lane >> 2)) * K + (lane & 3) * 8;
  u16* bldst0 = &L.s.b[wv * 1024];
  u16* bldst1 = &L.s.b[wv * 1024 + 512];

  for (int k0 = 0; k0 < K; k0 += 32){
    gl_lds16(asrc + k0, aldst);
    gl_lds16(bsrc0 + k0, bldst0);
    gl_lds16(bsrc1 + k0, bldst1);
    __syncthreads();
    short8 af[4], bf[4];
    #pragma unroll
    for (int m = 0; m < 4; m++)
      af[m] = *reinterpret_cast<const short8*>(&L.s.a[(wm * 64 + m * 16 + lr) * 32 + lk * 8]);
    #pragma unroll
    for (int n = 0; n < 4; n++)
      bf[n] = *reinterpret_cast<const short8*>(&L.s.b[(wn * 64 + n * 16 + lr) * 32 + lk * 8]);
    #pragma unroll
    for (int m = 0; m < 4; m++)
      #pragma unroll
      for (int n = 0; n < 4; n++)
        acc[m][n] = __builtin_amdgcn_mfma_f32_16x16x32_bf16(af[m], bf[n], acc[m][n], 0, 0, 0);
    __syncthreads();
  }

  int rg = lane >> 4;
  #pragma unroll
  for (int m = 0; m < 4; m++)
    #pragma unroll
    for (int n = 0; n < 4; n++)
      #pragma unroll
      for (int r = 0; r < 4; r++)
        L.ct[(wm * 64 + m * 16 + rg * 4 + r) * 256 + wn * 64 + n * 16 + lr] = f2b(acc[m][n][r]);
  __syncthreads();
  #pragma unroll
  for (int l = 0; l < 8; l++){
    int idx = t + l * 512;                 // 0..4095
    int row = idx >> 5, colg = idx & 31;
    short8 v = *reinterpret_cast<const short8*>(&L.ct[row * 256 + colg * 8]);
    *reinterpret_cast<short8*>(C + (size_t)(row0 + row) * 256 + colg * 8) = v;
  }

  // fused scores: thread t = (row r = t>>2 of tile, head hh = t&3)
  {
    int r = t >> 2, hh = t & 3;
    const u16* crow = &L.ct[r * 256 + hh * 64];
    float pl = 0.f, pr = 0.f;
    #pragma unroll
    for (int d8 = 0; d8 < 8; d8++){
      short8 cv = *reinterpret_cast<const short8*>(crow + d8 * 8);
      const float* alp = &attn_l[hh * 64 + d8 * 8];
      const float* arp = &attn_r[hh * 64 + d8 * 8];
      #pragma unroll
      for (int q = 0; q < 8; q++){
        float fv = b2f((u16)cv[q]);
        pl = fmaf(fv, alp[q], pl);
        pr = fmaf(fv, arp[q], pr);
      }
    }
    int orow = row0 + r;
    el[orow * 4 + hh] = pl;
    er[orow * 4 + hh] = pr;
  }
}

// ---------------- fused softmax + aggregation, no-max form --------------------------
// score lane map: slot=lane>>2 (edge), hs=lane&3 (head)
// agg   lane map: half=lane>>5 (edge parity), k=lane&31 -> features [8k,8k+8)
// LAYER 1: write bf16 h1[n][256].  LAYER 2: head-mean + atomic pooling by gid.
template<int LAYER>
__global__ __launch_bounds__(256) void k_agg2(const u16* __restrict__ feat,
    const float* __restrict__ el, const float* __restrict__ er,
    const int* __restrict__ offs, const int* __restrict__ bsum,
    const int* __restrict__ cnt, const int* __restrict__ csrc,
    const float* __restrict__ bias, const int* __restrict__ gid,
    void* __restrict__ outv)
{
  __shared__ int sb[64];
  block_bpre(bsum, sb);
  int wv = threadIdx.x >> 6, lane = threadIdx.x & 63;
  int n = blockIdx.x * 4 + wv;          // grid*4 == NN exactly
  int e0 = offs[n] + sb[n >> 10];
  int deg = cnt[n];
  int hs = lane & 3, slot = lane >> 2;
  int half = lane >> 5, k = lane & 31;
  int hk = k >> 3;                       // agg head of this lane
  float erh = er[n * 4 + hs];

  float srun_l = 0.f;
  float a[8];
  #pragma unroll
  for (int p = 0; p < 8; p++) a[p] = 0.f;

  for (int base = 0; base < deg; base += 16){
    int cntc = min(16, deg - base);
    int idx = base + slot;
    int sj = 0; float ex = 0.f;
    if (idx < deg){
      sj = csrc[e0 + idx];
      ex = __expf(leaky(el[sj * 4 + hs] + erh));
    }
    srun_l += ex;
    int jjmax = (cntc + 1) >> 1;
    for (int jj = 0; jj < jjmax; jj++){
      int e = jj * 2 + half;
      float w = __shfl(ex, e * 4 + hk);
      int sjj = __shfl(sj, e * 4);
      short8 fv = *reinterpret_cast<const short8*>(feat + (size_t)sjj * FH + k * 8);
      #pragma unroll
      for (int p = 0; p < 8; p++) a[p] = fmaf(w, b2f((u16)fv[p]), a[p]);
    }
  }

  #pragma unroll
  for (int d = 4; d < 64; d <<= 1) srun_l += __shfl_xor(srun_l, d);
  float invh = (deg > 0) ? 1.f / srun_l : 0.f;
  float inv = __shfl(invh, hk);
  #pragma unroll
  for (int p = 0; p < 8; p++) a[p] += __shfl_xor(a[p], 32);

  float4 bv0 = *reinterpret_cast<const float4*>(&bias[k * 8]);
  float4 bv1 = *reinterpret_cast<const float4*>(&bias[k * 8 + 4]);
  float ev[8];
  ev[0] = elu1(a[0] * inv + bv0.x); ev[1] = elu1(a[1] * inv + bv0.y);
  ev[2] = elu1(a[2] * inv + bv0.z); ev[3] = elu1(a[3] * inv + bv0.w);
  ev[4] = elu1(a[4] * inv + bv1.x); ev[5] = elu1(a[5] * inv + bv1.y);
  ev[6] = elu1(a[6] * inv + bv1.z); ev[7] = elu1(a[7] * inv + bv1.w);

  if (LAYER == 1){
    if (lane < 32){
      u16* out = (u16*)outv;
      short8 o;
      #pragma unroll
      for (int p = 0; p < 8; p++) o[p] = (short)f2b(ev[p]);
      *reinterpret_cast<short8*>(out + (size_t)n * FH + k * 8) = o;
    }
  } else {
    // head mean: sum lanes with same (k&7) across the 4 heads, then /4
    #pragma unroll
    for (int p = 0; p < 8; p++){
      ev[p] += __shfl_xor(ev[p], 8);
      ev[p] += __shfl_xor(ev[p], 16);
      ev[p] *= 0.25f;
    }
    if (lane < 8){
      float* pooled = (float*)outv;
      float* pg = pooled + gid[n] * HID + lane * 8;
      #pragma unroll
      for (int p = 0; p < 8; p++) atomicAdd(pg + p, ev[p]);
    }
  }
}

// ---------------- final FC ----------------
__global__ void k_fc(const float* __restrict__ pooled, const float* __restrict__ fcW,
                     const float* __restrict__ fcb, float* __restrict__ out)
{
  int t = threadIdx.x;
  if (t >= NG * NOUT) return;
  int g = t / NOUT, o = t % NOUT;
  float s = fcb[o];
  for (int d = 0; d < HID; d++) s = fmaf(pooled[g * HID + d], fcW[d * NOUT + o], s);
  out[t] = s;
}

static inline size_t align_up(size_t x){ return (x + 255) & ~(size_t)255; }

extern "C" void kernel_launch(void* const* d_in, const int* in_sizes, int n_in,
                              void* d_out, int out_size, void* d_ws, size_t ws_size,
                              hipStream_t stream) {
  const float* x    = (const float*)d_in[0];
  const int*   src  = (const int*)d_in[1];
  const int*   dst  = (const int*)d_in[2];
  const int*   gid  = (const int*)d_in[3];
  const float* W1   = (const float*)d_in[4];
  const float* al1  = (const float*)d_in[5];
  const float* ar1  = (const float*)d_in[6];
  const float* b1   = (const float*)d_in[7];
  const float* W2   = (const float*)d_in[8];
  const float* al2  = (const float*)d_in[9];
  const float* ar2  = (const float*)d_in[10];
  const float* b2   = (const float*)d_in[11];
  const float* fcW  = (const float*)d_in[12];
  const float* fcb  = (const float*)d_in[13];
  float* out = (float*)d_out;

  char* p = (char*)d_ws;
  int* cnt  = (int*)p; p += align_up((size_t)NN * 4);
  int* offs = (int*)p; p += align_up((size_t)NN * 4);
  int* bsum = (int*)p; p += align_up((size_t)NSB * 4);
  int* rank = (int*)p; p += align_up((size_t)NE * 4);
  int* csrc = (int*)p; p += align_up((size_t)NE * 4);
  u16* xh    = (u16*)p; p += align_up((size_t)MPAD * FIN * 2);
  u16* feath = (u16*)p; p += align_up((size_t)MPAD * FH * 2);
  u16* h1h   = (u16*)p; p += align_up((size_t)MPAD * FH * 2);
  float* elb = (float*)p; p += align_up((size_t)MPAD * NH * 4);
  float* erb = (float*)p; p += align_up((size_t)MPAD * NH * 4);
  float* pooled = (float*)p; p += align_up((size_t)NG * HID * 4);
  u16* Wt1 = (u16*)p; p += align_up((size_t)FIN * FH * 2);
  u16* Wt2 = (u16*)p; p += align_up((size_t)FH * FH * 2);

  hipMemsetAsync(cnt, 0, (size_t)NN * 4, stream);

  const int EB = (NE + 255) / 256;      // 3125
  const int NB4 = (NN + 3) / 4;         // 12500
  const int GB = MPAD / 128;            // 391
  const int HP = HIST_BLKS + F2B_BLKS + W1_BLKS + W2_BLKS + 1;

  k_histprep<<<HP, 256, 0, stream>>>(dst, cnt, rank, x, xh, W1, Wt1, W2, Wt2, pooled);
  k_scan1<<<NSB, 256, 0, stream>>>(cnt, offs, bsum);
  k_scatter<<<EB, 256, 0, stream>>>(src, dst, offs, bsum, rank, csrc);

  // layer 1
  k_gemm_bf<FIN><<<GB, 512, 0, stream>>>(xh, Wt1, feath, al1, ar1, elb, erb);
  k_agg2<1><<<NB4, 256, 0, stream>>>(feath, elb, erb, offs, bsum, cnt, csrc, b1, gid, h1h);

  // layer 2 (agg fused with graph pooling via atomics)
  k_gemm_bf<FH><<<GB, 512, 0, stream>>>(h1h, Wt2, feath, al2, ar2, elb, erb);
  k_agg2<2><<<NB4, 256, 0, stream>>>(feath, elb, erb, offs, bsum, cnt, csrc, b2, gid, pooled);

  // FC
  k_fc<<<1, 640, 0, stream>>>(pooled, fcW, fcb, out);
}

// Round 15
// 270.200 us; speedup vs baseline: 2.7489x; 2.7489x over previous
//
#include <hip/hip_runtime.h>
#include <math.h>

#define NN 50000
#define MPAD 50048   // 391 * 128
#define NE 800000
#define NG 64
#define FIN 128
#define FH 256      // heads * HID = 4*64, both layers
#define HID 64
#define NH 4
#define NOUT 10
#define NEG_SLOPE 0.2f
#define NSB ((NN + 1023) / 1024)   // 49 scan blocks

typedef unsigned short u16;
typedef __attribute__((ext_vector_type(8))) short short8;
typedef __attribute__((ext_vector_type(4))) float f32x4;

static __device__ __forceinline__ float leaky(float x){ return x > 0.f ? x : NEG_SLOPE * x; }
static __device__ __forceinline__ float elu1(float x){ return x > 0.f ? x : (__expf(x) - 1.f); }
static __device__ __forceinline__ float b2f(u16 u){
  union { unsigned int i; float f; } v; v.i = ((unsigned)u) << 16; return v.f;
}
static __device__ __forceinline__ u16 f2b(float f){
  union { float f; unsigned int i; } v; v.f = f;
  unsigned r = v.i + 0x7FFFu + ((v.i >> 16) & 1u);
  return (u16)(r >> 16);
}

static __device__ __forceinline__ void gl_lds16(const u16* g, u16* l){
  __builtin_amdgcn_global_load_lds(
      (const __attribute__((address_space(1))) void*)g,
      (__attribute__((address_space(3))) void*)l, 16, 0, 0);
}

// ---------------- fused: hist (+rank), x->bf16, W transposes (pure bf16), pooled zero
#define HIST_BLKS ((NE + 255) / 256)           // 3125
#define F2B_BLKS (NN * FIN / 4 / 256)          // 6250
#define W1_BLKS  (FIN * FH / 256)              // 128
#define W2_BLKS  (FH * FH / 256)               // 256
__global__ void k_histprep(const int* __restrict__ dst, int* __restrict__ cnt,
                           int* __restrict__ rank,
                           const float* __restrict__ x, u16* __restrict__ xh,
                           const float* __restrict__ W1, u16* __restrict__ Wt1,
                           const float* __restrict__ W2, u16* __restrict__ Wt2,
                           float* __restrict__ pooled)
{
  int b = blockIdx.x;
  if (b < HIST_BLKS){
    int i = b * 256 + threadIdx.x;
    if (i < NE) rank[i] = atomicAdd(&cnt[dst[i]], 1);
  } else if (b < HIST_BLKS + F2B_BLKS){
    int i = ((b - HIST_BLKS) * 256 + threadIdx.x) * 4;
    float4 v = *reinterpret_cast<const float4*>(x + i);
    ushort4 o; o.x = f2b(v.x); o.y = f2b(v.y); o.z = f2b(v.z); o.w = f2b(v.w);
    *reinterpret_cast<ushort4*>(xh + i) = o;
  } else if (b < HIST_BLKS + F2B_BLKS + W1_BLKS){
    int e = (b - HIST_BLKS - F2B_BLKS) * 256 + threadIdx.x;
    int k = e >> 8, c = e & 255;
    Wt1[(size_t)c * FIN + k] = f2b(W1[e]);
  } else if (b < HIST_BLKS + F2B_BLKS + W1_BLKS + W2_BLKS){
    int e = (b - HIST_BLKS - F2B_BLKS - W1_BLKS) * 256 + threadIdx.x;
    int k = e >> 8, c = e & 255;
    Wt2[(size_t)c * FH + k] = f2b(W2[e]);
  } else {
    float4 z = make_float4(0.f, 0.f, 0.f, 0.f);
    #pragma unroll
    for (int l = 0; l < 4; l++)
      *reinterpret_cast<float4*>(pooled + (l * 256 + threadIdx.x) * 4) = z;
  }
}

// scan stage 1: per-1024-chunk LOCAL exclusive prefix + block total
__global__ __launch_bounds__(256) void k_scan1(const int* __restrict__ cnt,
    int* __restrict__ offs, int* __restrict__ bsum)
{
  __shared__ int wsum[4];
  int t = threadIdx.x;
  int lane = t & 63, wv = t >> 6;
  int base = blockIdx.x * 1024 + t * 4;
  int4 v = make_int4(0, 0, 0, 0);
  if (base + 3 < NN) v = *reinterpret_cast<const int4*>(cnt + base);
  else {
    if (base + 0 < NN) v.x = cnt[base + 0];
    if (base + 1 < NN) v.y = cnt[base + 1];
    if (base + 2 < NN) v.z = cnt[base + 2];
  }
  int s = v.x + v.y + v.z + v.w;
  int incl = s;
  #pragma unroll
  for (int d = 1; d < 64; d <<= 1){
    int u = __shfl_up(incl, d);
    if (lane >= d) incl += u;
  }
  if (lane == 63) wsum[wv] = incl;
  __syncthreads();
  int woff = 0;
  #pragma unroll
  for (int i = 0; i < 4; i++) if (i < wv) woff += wsum[i];
  int texcl = woff + incl - s;
  int e0 = texcl, e1 = e0 + v.x, e2 = e1 + v.y, e3 = e2 + v.z;
  if (base + 3 < NN) *reinterpret_cast<int4*>(offs + base) = make_int4(e0, e1, e2, e3);
  else {
    if (base + 0 < NN) offs[base + 0] = e0;
    if (base + 1 < NN) offs[base + 1] = e1;
    if (base + 2 < NN) offs[base + 2] = e2;
  }
  if (t == 255) bsum[blockIdx.x] = woff + incl;
}

// per-block inline scan of the 49 block totals -> LDS (wave 0 computes)
static __device__ __forceinline__ void block_bpre(const int* __restrict__ bsum,
                                                  int* sb)
{
  int t = threadIdx.x;
  if (t < 64){
    int s = (t < NSB) ? bsum[t] : 0;
    int incl = s;
    #pragma unroll
    for (int d = 1; d < 64; d <<= 1){
      int u = __shfl_up(incl, d);
      if (t >= d) incl += u;
    }
    sb[t] = incl - s;
  }
  __syncthreads();
}

// atomic-free scatter; global offset = local offs + block prefix
__global__ __launch_bounds__(256) void k_scatter(const int* __restrict__ src,
    const int* __restrict__ dst, const int* __restrict__ offs,
    const int* __restrict__ bsum, const int* __restrict__ rank,
    int* __restrict__ csrc){
  __shared__ int sb[64];
  block_bpre(bsum, sb);
  int i = blockIdx.x * blockDim.x + threadIdx.x;
  if (i < NE){
    int d = dst[i];
    csrc[offs[d] + sb[d >> 10] + rank[i]] = src[i];
  }
}

// ---------------- bf16 MFMA GEMM (128x256 tile, 8 waves) + fused attention scores ----
// C[MPAD][256] = A[MPAD][K] @ Wt^T, Wt[256][K] bf16
template<int K>
__global__ __launch_bounds__(512) void k_gemm_bf(
    const u16* __restrict__ A, const u16* __restrict__ Wt, u16* __restrict__ C,
    const float* __restrict__ attn_l, const float* __restrict__ attn_r,
    float* __restrict__ el, float* __restrict__ er)
{
  __shared__ union {
    struct { u16 a[128 * 32]; u16 b[256 * 32]; } s;  // 8KB + 16KB
    u16 ct[128 * 256];                               // 64KB epilogue staging
  } L;
  int t = threadIdx.x;
  int wv = t >> 6, lane = t & 63;
  int row0 = blockIdx.x * 128;
  int lr = lane & 15, lk = lane >> 4;
  int wm = wv >> 2, wn = wv & 3;       // wave grid 2 x 4

  f32x4 acc[4][4];
  #pragma unroll
  for (int m = 0; m < 4; m++)
    #pragma unroll
    for (int n = 0; n < 4; n++) acc[m][n] = (f32x4){0.f, 0.f, 0.f, 0.f};

  const u16* asrc = A + (size_t)(row0 + wv * 16 + (lane >> 2)) * K + (lane & 3) * 8;
  u16* aldst = &L.s.a[wv * 512];
  const u16* bsrc0 = Wt + (size_t)(wv * 32 + (lane >> 2)) * K + (lane & 3) * 8;
  const u16* bsrc1 = Wt + (size_t)(wv * 32 + 16 + (lane >> 2)) * K + (lane & 3) * 8;
  u16* bldst0 = &L.s.b[wv * 1024];
  u16* bldst1 = &L.s.b[wv * 1024 + 512];

  for (int k0 = 0; k0 < K; k0 += 32){
    gl_lds16(asrc + k0, aldst);
    gl_lds16(bsrc0 + k0, bldst0);
    gl_lds16(bsrc1 + k0, bldst1);
    __syncthreads();
    short8 af[4], bf[4];
    #pragma unroll
    for (int m = 0; m < 4; m++)
      af[m] = *reinterpret_cast<const short8*>(&L.s.a[(wm * 64 + m * 16 + lr) * 32 + lk * 8]);
    #pragma unroll
    for (int n = 0; n < 4; n++)
      bf[n] = *reinterpret_cast<const short8*>(&L.s.b[(wn * 64 + n * 16 + lr) * 32 + lk * 8]);
    #pragma unroll
    for (int m = 0; m < 4; m++)
      #pragma unroll
      for (int n = 0; n < 4; n++)
        acc[m][n] = __builtin_amdgcn_mfma_f32_16x16x32_bf16(af[m], bf[n], acc[m][n], 0, 0, 0);
    __syncthreads();
  }

  int rg = lane >> 4;
  #pragma unroll
  for (int m = 0; m < 4; m++)
    #pragma unroll
    for (int n = 0; n < 4; n++)
      #pragma unroll
      for (int r = 0; r < 4; r++)
        L.ct[(wm * 64 + m * 16 + rg * 4 + r) * 256 + wn * 64 + n * 16 + lr] = f2b(acc[m][n][r]);
  __syncthreads();
  #pragma unroll
  for (int l = 0; l < 8; l++){
    int idx = t + l * 512;                 // 0..4095
    int row = idx >> 5, colg = idx & 31;
    short8 v = *reinterpret_cast<const short8*>(&L.ct[row * 256 + colg * 8]);
    *reinterpret_cast<short8*>(C + (size_t)(row0 + row) * 256 + colg * 8) = v;
  }

  // fused scores: thread t = (row r = t>>2 of tile, head hh = t&3)
  {
    int r = t >> 2, hh = t & 3;
    const u16* crow = &L.ct[r * 256 + hh * 64];
    float pl = 0.f, pr = 0.f;
    #pragma unroll
    for (int d8 = 0; d8 < 8; d8++){
      short8 cv = *reinterpret_cast<const short8*>(crow + d8 * 8);
      const float* alp = &attn_l[hh * 64 + d8 * 8];
      const float* arp = &attn_r[hh * 64 + d8 * 8];
      #pragma unroll
      for (int q = 0; q < 8; q++){
        float fv = b2f((u16)cv[q]);
        pl = fmaf(fv, alp[q], pl);
        pr = fmaf(fv, arp[q], pr);
      }
    }
    int orow = row0 + r;
    el[orow * 4 + hh] = pl;
    er[orow * 4 + hh] = pr;
  }
}

// ---------------- fused softmax + aggregation, no-max form --------------------------
// score lane map: slot=lane>>2 (edge), hs=lane&3 (head)
// agg   lane map: half=lane>>5 (edge parity), k=lane&31 -> features [8k,8k+8)
template<int LAYER>
__global__ __launch_bounds__(256) void k_agg2(const u16* __restrict__ feat,
    const float* __restrict__ el, const float* __restrict__ er,
    const int* __restrict__ offs, const int* __restrict__ bsum,
    const int* __restrict__ cnt, const int* __restrict__ csrc,
    const float* __restrict__ bias, void* __restrict__ outv)
{
  __shared__ int sb[64];
  block_bpre(bsum, sb);
  int wv = threadIdx.x >> 6, lane = threadIdx.x & 63;
  int n = blockIdx.x * 4 + wv;          // grid*4 == NN exactly
  int e0 = offs[n] + sb[n >> 10];
  int deg = cnt[n];
  int hs = lane & 3, slot = lane >> 2;
  int half = lane >> 5, k = lane & 31;
  int hk = k >> 3;                       // agg head of this lane
  float erh = er[n * 4 + hs];

  float srun_l = 0.f;
  float a[8];
  #pragma unroll
  for (int p = 0; p < 8; p++) a[p] = 0.f;

  for (int base = 0; base < deg; base += 16){
    int cntc = min(16, deg - base);
    int idx = base + slot;
    int sj = 0; float ex = 0.f;
    if (idx < deg){
      sj = csrc[e0 + idx];
      ex = __expf(leaky(el[sj * 4 + hs] + erh));
    }
    srun_l += ex;
    int jjmax = (cntc + 1) >> 1;
    for (int jj = 0; jj < jjmax; jj++){
      int e = jj * 2 + half;
      float w = __shfl(ex, e * 4 + hk);
      int sjj = __shfl(sj, e * 4);
      short8 fv = *reinterpret_cast<const short8*>(feat + (size_t)sjj * FH + k * 8);
      #pragma unroll
      for (int p = 0; p < 8; p++) a[p] = fmaf(w, b2f((u16)fv[p]), a[p]);
    }
  }

  #pragma unroll
  for (int d = 4; d < 64; d <<= 1) srun_l += __shfl_xor(srun_l, d);
  float invh = (deg > 0) ? 1.f / srun_l : 0.f;
  float inv = __shfl(invh, hk);
  #pragma unroll
  for (int p = 0; p < 8; p++) a[p] += __shfl_xor(a[p], 32);

  float4 bv0 = *reinterpret_cast<const float4*>(&bias[k * 8]);
  float4 bv1 = *reinterpret_cast<const float4*>(&bias[k * 8 + 4]);
  float ev[8];
  ev[0] = elu1(a[0] * inv + bv0.x); ev[1] = elu1(a[1] * inv + bv0.y);
  ev[2] = elu1(a[2] * inv + bv0.z); ev[3] = elu1(a[3] * inv + bv0.w);
  ev[4] = elu1(a[4] * inv + bv1.x); ev[5] = elu1(a[5] * inv + bv1.y);
  ev[6] = elu1(a[6] * inv + bv1.z); ev[7] = elu1(a[7] * inv + bv1.w);

  if (LAYER == 1){
    if (lane < 32){
      u16* out = (u16*)outv;
      short8 o;
      #pragma unroll
      for (int p = 0; p < 8; p++) o[p] = (short)f2b(ev[p]);
      *reinterpret_cast<short8*>(out + (size_t)n * FH + k * 8) = o;
    }
  } else {
    #pragma unroll
    for (int p = 0; p < 8; p++){
      ev[p] += __shfl_xor(ev[p], 8);
      ev[p] += __shfl_xor(ev[p], 16);
      ev[p] *= 0.25f;
    }
    if (lane < 8){
      float* out = (float*)outv;
      float4 o0 = make_float4(ev[0], ev[1], ev[2], ev[3]);
      float4 o1 = make_float4(ev[4], ev[5], ev[6], ev[7]);
      *reinterpret_cast<float4*>(out + (size_t)n * HID + lane * 8) = o0;
      *reinterpret_cast<float4*>(out + (size_t)n * HID + lane * 8 + 4) = o1;
    }
  }
}

// ---------------- graph sum-pooling: 1 wave per 64-node chunk ----------------
__global__ __launch_bounds__(256) void k_pool(const float* __restrict__ h2,
    const int* __restrict__ gid, float* __restrict__ pooled)
{
  int wv = threadIdx.x >> 6, lane = threadIdx.x & 63;
  int w = blockIdx.x * 4 + wv;
  int base = w * 64;
  if (base >= NN) return;
  int grp = lane >> 4, c4 = (lane & 15) * 4;
  int curg = -1;
  float4 acc = make_float4(0.f, 0.f, 0.f, 0.f);
  #pragma unroll 4
  for (int it = 0; it < 16; it++){
    int row = base + it * 4 + grp;
    if (row >= NN) break;
    int g = gid[row];
    if (g != curg){
      if (curg >= 0){
        atomicAdd(&pooled[curg * HID + c4 + 0], acc.x);
        atomicAdd(&pooled[curg * HID + c4 + 1], acc.y);
        atomicAdd(&pooled[curg * HID + c4 + 2], acc.z);
        atomicAdd(&pooled[curg * HID + c4 + 3], acc.w);
      }
      curg = g; acc = make_float4(0.f, 0.f, 0.f, 0.f);
    }
    float4 v = *reinterpret_cast<const float4*>(&h2[(size_t)row * HID + c4]);
    acc.x += v.x; acc.y += v.y; acc.z += v.z; acc.w += v.w;
  }
  if (curg >= 0){
    atomicAdd(&pooled[curg * HID + c4 + 0], acc.x);
    atomicAdd(&pooled[curg * HID + c4 + 1], acc.y);
    atomicAdd(&pooled[curg * HID + c4 + 2], acc.z);
    atomicAdd(&pooled[curg * HID + c4 + 3], acc.w);
  }
}

// ---------------- final FC ----------------
__global__ void k_fc(const float* __restrict__ pooled, const float* __restrict__ fcW,
                     const float* __restrict__ fcb, float* __restrict__ out)
{
  int t = threadIdx.x;
  if (t >= NG * NOUT) return;
  int g = t / NOUT, o = t % NOUT;
  float s = fcb[o];
  for (int d = 0; d < HID; d++) s = fmaf(pooled[g * HID + d], fcW[d * NOUT + o], s);
  out[t] = s;
}

static inline size_t align_up(size_t x){ return (x + 255) & ~(size_t)255; }

extern "C" void kernel_launch(void* const* d_in, const int* in_sizes, int n_in,
                              void* d_out, int out_size, void* d_ws, size_t ws_size,
                              hipStream_t stream) {
  const float* x    = (const float*)d_in[0];
  const int*   src  = (const int*)d_in[1];
  const int*   dst  = (const int*)d_in[2];
  const int*   gid  = (const int*)d_in[3];
  const float* W1   = (const float*)d_in[4];
  const float* al1  = (const float*)d_in[5];
  const float* ar1  = (const float*)d_in[6];
  const float* b1   = (const float*)d_in[7];
  const float* W2   = (const float*)d_in[8];
  const float* al2  = (const float*)d_in[9];
  const float* ar2  = (const float*)d_in[10];
  const float* b2   = (const float*)d_in[11];
  const float* fcW  = (const float*)d_in[12];
  const float* fcb  = (const float*)d_in[13];
  float* out = (float*)d_out;

  char* p = (char*)d_ws;
  int* cnt  = (int*)p; p += align_up((size_t)NN * 4);
  int* offs = (int*)p; p += align_up((size_t)NN * 4);
  int* bsum = (int*)p; p += align_up((size_t)NSB * 4);
  int* rank = (int*)p; p += align_up((size_t)NE * 4);
  int* csrc = (int*)p; p += align_up((size_t)NE * 4);
  u16* xh    = (u16*)p; p += align_up((size_t)MPAD * FIN * 2);
  u16* feath = (u16*)p; p += align_up((size_t)MPAD * FH * 2);
  u16* h1h   = (u16*)p; p += align_up((size_t)MPAD * FH * 2);
  float* elb = (float*)p; p += align_up((size_t)MPAD * NH * 4);
  float* erb = (float*)p; p += align_up((size_t)MPAD * NH * 4);
  float* h2  = (float*)p; p += align_up((size_t)NN * HID * 4);
  float* pooled = (float*)p; p += align_up((size_t)NG * HID * 4);
  u16* Wt1 = (u16*)p; p += align_up((size_t)FIN * FH * 2);
  u16* Wt2 = (u16*)p; p += align_up((size_t)FH * FH * 2);

  hipMemsetAsync(cnt, 0, (size_t)NN * 4, stream);

  const int EB = (NE + 255) / 256;      // 3125
  const int NB4 = (NN + 3) / 4;         // 12500
  const int GB = MPAD / 128;            // 391
  const int HP = HIST_BLKS + F2B_BLKS + W1_BLKS + W2_BLKS + 1;

  k_histprep<<<HP, 256, 0, stream>>>(dst, cnt, rank, x, xh, W1, Wt1, W2, Wt2, pooled);
  k_scan1<<<NSB, 256, 0, stream>>>(cnt, offs, bsum);
  k_scatter<<<EB, 256, 0, stream>>>(src, dst, offs, bsum, rank, csrc);

  // layer 1
  k_gemm_bf<FIN><<<GB, 512, 0, stream>>>(xh, Wt1, feath, al1, ar1, elb, erb);
  k_agg2<1><<<NB4, 256, 0, stream>>>(feath, elb, erb, offs, bsum, cnt, csrc, b1, h1h);

  // layer 2
  k_gemm_bf<FH><<<GB, 512, 0, stream>>>(h1h, Wt2, feath, al2, ar2, elb, erb);
  k_agg2<2><<<NB4, 256, 0, stream>>>(feath, elb, erb, offs, bsum, cnt, csrc, b2, h2);

  // pooling + FC
  k_pool<<<(NN + 255) / 256, 256, 0, stream>>>(h2, gid, pooled);
  k_fc<<<1, 640, 0, stream>>>(pooled, fcW, fcb, out);
}